// Round 13
// baseline (181.411 us; speedup 1.0000x reference)
//
#include <hip/hip_runtime.h>
#include <hip/hip_bf16.h>

#define BB 4
#define CC 32
#define WW 256
#define HH 256
#define WH (WW*HH)

typedef __attribute__((ext_vector_type(8))) short bf16x8;
typedef __attribute__((ext_vector_type(4))) short bf16x4;
typedef __attribute__((ext_vector_type(4))) float f32x4;

typedef __attribute__((address_space(1))) const void gvoid;
typedef __attribute__((address_space(3))) void lvoid;

__device__ __forceinline__ short f2bf(float x) {   // RNE fp32->bf16
    union { float f; unsigned u; } a; a.f = x;
    unsigned r = (a.u + 0x7FFF + ((a.u >> 16) & 1)) >> 16;
    return (short)r;
}

// ---------------- K0: build B-fragment tables (bf16, frag-linear) + zero stats ----
__global__ void k0_init(const float* __restrict__ w_dsc, const float* __restrict__ w_off,
                        unsigned short* __restrict__ B3f, unsigned short* __restrict__ B8f,
                        unsigned short* __restrict__ B1f, unsigned short* __restrict__ B18f,
                        float* __restrict__ stats1, float* __restrict__ stats2) {
    int i = blockIdx.x * 256 + threadIdx.x;
    if (i < 8192) {                       // k3 main: [ch][nt][lane][j]
        int j = i & 7, l = (i >> 3) & 63, nt = (i >> 9) & 1, ch = i >> 10;
        int o = nt * 16 + (l & 15);
        int kl = ((l >> 4) << 3) | j;
        int tap = kl >> 2, cl = kl & 3;
        B3f[i] = (unsigned short)f2bf(w_dsc[(o * 32 + ch * 4 + cl) * 9 + tap]);
    } else if (i < 9216) {                // k3 tap8: [nt][lane][j], k8 = channel
        int e = i - 8192;
        int j = e & 7, l = (e >> 3) & 63, nt = e >> 9;
        int o = nt * 16 + (l & 15);
        int k8 = ((l >> 4) << 3) | j;
        B8f[e] = (unsigned short)f2bf(w_dsc[(o * 32 + k8) * 9 + 8]);
    } else if (i < 13312) {               // k1 main: [ch][lane][j], N=16 (10 real)
        int e = i - 9216;
        int j = e & 7, l = (e >> 3) & 63, ch = e >> 9;
        int o = l & 15;
        int kl = ((l >> 4) << 3) | j;
        int tap = kl >> 2, cl = kl & 3;
        B1f[e] = (o < 10) ? (unsigned short)f2bf(w_off[(o * 32 + ch * 4 + cl) * 9 + tap]) : 0;
    } else if (i < 13824) {               // k1 tap8
        int e = i - 13312;
        int j = e & 7, l = (e >> 3) & 63;
        int o = l & 15;
        int k8 = ((l >> 4) << 3) | j;
        B18f[e] = (o < 10) ? (unsigned short)f2bf(w_off[(o * 32 + k8) * 9 + 8]) : 0;
    }
    if (i < 40) stats1[i] = 0.f;
    if (i < 64) stats2[i] = 0.f;
}

// ---------------- K1: 3x3 SAME conv (10 oc) as implicit MFMA GEMM ----------------
// R11 form (passing): full-tile channel-last staging + direct A-fragment reads.
// UNCHANGED.
__global__ __launch_bounds__(256, 4) void k1_conv(
    const float* __restrict__ x, const unsigned short* __restrict__ B1f,
    const unsigned short* __restrict__ B18f, const float* __restrict__ b_off,
    float* __restrict__ off_buf, float* __restrict__ stats1) {
    __shared__ __align__(16) unsigned short tbf[8 * 4 * 136 * 4];  // 34,816 B
    __shared__ float scr[40];

    const int b = blockIdx.z;
    const int w0 = blockIdx.y * 2;
    const int h0 = blockIdx.x * 128;
    const int p = threadIdx.x;
    const int lane = p & 63;
    const int wv = p >> 6;

    const float* xb = x + (size_t)b * CC * WH;

#pragma unroll
    for (int u = 0; u < 5; ++u) {
        if (u < 4 || p < 64) {
            int s = p + u * 256;
            int g = s / 136;
            int rem = s - g * 136;
            int r = rem / 34;
            int k = rem - r * 34;
            int y = w0 - 1 + r;
            int g0 = h0 - 4 + (k << 2);
            f32x4 v0 = {0.f,0.f,0.f,0.f}, v1 = v0, v2 = v0, v3 = v0;
            if (y >= 0 && y < 256 && g0 >= 0 && g0 <= 252) {
                const float* bp2 = xb + y * 256 + g0;
                v0 = *(const f32x4*)(bp2 + (size_t)(g * 4 + 0) * WH);
                v1 = *(const f32x4*)(bp2 + (size_t)(g * 4 + 1) * WH);
                v2 = *(const f32x4*)(bp2 + (size_t)(g * 4 + 2) * WH);
                v3 = *(const f32x4*)(bp2 + (size_t)(g * 4 + 3) * WH);
            }
            int base = ((g * 4 + r) * 136 + (k << 2)) * 4;
#pragma unroll
            for (int i = 0; i < 4; ++i) {
                bf16x4 pv;
                pv[0] = f2bf(v0[i]); pv[1] = f2bf(v1[i]);
                pv[2] = f2bf(v2[i]); pv[3] = f2bf(v3[i]);
                *(bf16x4*)&tbf[base + i * 4] = pv;
            }
        }
    }

    bf16x8 Bf[8], B8g;
    {
        const bf16x8* bp = (const bf16x8*)B1f;
#pragma unroll
        for (int ch = 0; ch < 8; ++ch) Bf[ch] = bp[ch * 64 + lane];
        B8g = ((const bf16x8*)B18f)[lane];
    }

    f32x4 acc[4];
#pragma unroll
    for (int i = 0; i < 4; ++i) acc[i] = (f32x4){0.f, 0.f, 0.f, 0.f};

    const int kg = lane >> 4;
    const int tapL = kg * 2, tapH = tapL + 1;
    const int dyL = tapL / 3, dxL = tapL - dyL * 3;
    const int dyH = tapH / 3, dxH = tapH - dyH * 3;
    int loA[4], hiA[4], t8A[4];
#pragma unroll
    for (int i = 0; i < 4; ++i) {
        int pp = (wv * 4 + i) * 16 + (lane & 15);
        int hlp = pp & 127, wip = pp >> 7;
        loA[i] = ((wip + dyL) * 136 + hlp + dxL + 3) * 4;
        hiA[i] = ((wip + dyH) * 136 + hlp + dxH + 3) * 4;
        t8A[i] = (((kg * 2) * 4 + wip + 2) * 136 + hlp + 5) * 4;
    }

    __syncthreads();   // tile staged; read-only below

#pragma unroll
    for (int ch = 0; ch < 8; ++ch) {
        const int cb = ch * 2176;
#pragma unroll
        for (int i = 0; i < 4; ++i) {
            bf16x4 lo = *(const bf16x4*)&tbf[cb + loA[i]];
            bf16x4 hi = *(const bf16x4*)&tbf[cb + hiA[i]];
            bf16x8 a;
#pragma unroll
            for (int e = 0; e < 4; ++e) { a[e] = lo[e]; a[4 + e] = hi[e]; }
            acc[i] = __builtin_amdgcn_mfma_f32_16x16x32_bf16(a, Bf[ch], acc[i], 0, 0, 0);
        }
    }
#pragma unroll
    for (int i = 0; i < 4; ++i) {          // tap8 K=32 block: k8 = channel
        bf16x4 lo = *(const bf16x4*)&tbf[t8A[i]];
        bf16x4 hi = *(const bf16x4*)&tbf[t8A[i] + 2176];
        bf16x8 a;
#pragma unroll
        for (int e = 0; e < 4; ++e) { a[e] = lo[e]; a[4 + e] = hi[e]; }
        acc[i] = __builtin_amdgcn_mfma_f32_16x16x32_bf16(a, B8g, acc[i], 0, 0, 0);
    }

    const int oc = lane & 15;
    float bias = (oc < 10) ? b_off[oc] : 0.f;
#pragma unroll
    for (int i = 0; i < 4; ++i)
#pragma unroll
        for (int r = 0; r < 4; ++r) acc[i][r] += bias;

    if (oc < 10) {
#pragma unroll
        for (int i = 0; i < 4; ++i) {
            int px = (wv * 4 + i) * 16 + (lane >> 4) * 4;
            size_t addr = (size_t)(b * 10 + oc) * WH +
                          (size_t)(w0 + (px >> 7)) * 256 + h0 + (px & 127);
            *(f32x4*)&off_buf[addr] = acc[i];
        }
    }

    // GN1 stats from C-frags (cols = oc; oc>=10 are exact zeros)
    float s = 0.f, q = 0.f;
#pragma unroll
    for (int i = 0; i < 4; ++i)
#pragma unroll
        for (int r = 0; r < 4; ++r) { float v = acc[i][r]; s += v; q += v * v; }
    s += __shfl_xor(s, 1, 64);  q += __shfl_xor(q, 1, 64);
    s += __shfl_xor(s, 16, 64); q += __shfl_xor(q, 16, 64);
    s += __shfl_xor(s, 32, 64); q += __shfl_xor(q, 32, 64);
    __syncthreads();
    if (lane < 10 && !(lane & 1)) {
        int g = lane >> 1;
        scr[(g * 2 + 0) * 4 + wv] = s;
        scr[(g * 2 + 1) * 4 + wv] = q;
    }
    __syncthreads();
    if (threadIdx.x < 10) {
        int g = threadIdx.x >> 1, which = threadIdx.x & 1;
        float sum = scr[(g * 2 + which) * 4 + 0] + scr[(g * 2 + which) * 4 + 1] +
                    scr[(g * 2 + which) * 4 + 2] + scr[(g * 2 + which) * 4 + 3];
        atomicAdd(&stats1[(b * 5 + g) * 2 + which], sum);
    }
}

// ---------------- K3: bilinear sampling as implicit MFMA GEMM ---------------------
// R10/R11 form (passing, 63-64 us): DMA double-buffer + explicit vmcnt(0) drains.
// UNCHANGED (R12 lane-direct restructure reverted after correctness failure).
__global__ __launch_bounds__(256, 2) void k3_sample(
    const float* __restrict__ xin, const float* __restrict__ off_buf,
    const float* __restrict__ stats1, const float* __restrict__ go_scale,
    const float* __restrict__ go_bias, const unsigned short* __restrict__ B3f,
    const unsigned short* __restrict__ B8f, const float* __restrict__ b_dsc,
    float* __restrict__ pre_out, float* __restrict__ stats2) {
    __shared__ __align__(16) float tile[2][4 * 14 * 96];  // 2 x 21,504 B
    __shared__ __align__(16) short Apan[16 * 64 * 8];     // 16 KB
    __shared__ __align__(16) short A8pan[16 * 64 * 8];    // 16 KB

    const int b = blockIdx.z;
    const int w0 = blockIdx.y * 4;
    const int h0 = blockIdx.x * 64;
    const int p = threadIdx.x;
    const int lane = p & 63;
    const int wv = p >> 6;
    const int h = h0 + (p & 63);
    const int w = w0 + (p >> 6);
    const int mt = p >> 4;
    const int mrow = p & 15;
    const int row0 = w0 - 5;
    const int col0 = h0 - 8;

    const float* xb = xin + (size_t)b * CC * WH;

    auto dma = [&](int buf, int chn) {
#pragma unroll
        for (int u = 0; u < 6; ++u) {
            if (u < 5 || p < 64) {
                int t = p + u * 256;
                int c = t / 336;
                int rem = t - c * 336;
                int r = rem / 24;
                int cf4 = rem - r * 24;
                int y = min(max(row0 + r, 0), 255);
                int g0 = min(max(col0 + (cf4 << 2), 0), 252);
                const float* gp = xb + (size_t)(chn * 4 + c) * WH + y * 256 + g0;
                __builtin_amdgcn_global_load_lds((gvoid*)gp,
                                                 (lvoid*)&tile[buf][t * 4], 16, 0, 0);
            }
        }
    };

    dma(0, 0);   // in flight under B-frag loads + offsets/tanh phase

    bf16x8 Bf[8][2], B8g[2];
    {
        const bf16x8* bp = (const bf16x8*)B3f;
#pragma unroll
        for (int ch = 0; ch < 8; ++ch) {
            Bf[ch][0] = bp[(ch * 2 + 0) * 64 + lane];
            Bf[ch][1] = bp[(ch * 2 + 1) * 64 + lane];
        }
        B8g[0] = ((const bf16x8*)B8f)[lane];
        B8g[1] = ((const bf16x8*)B8f)[64 + lane];
    }

    // offsets: GN1 (inline finalize from stats1) + tanh + cumsum (per own pixel)
    const float INV1 = 1.f / (2.f * WH);   // 2^-17, exact
    float t9[9];
    size_t obase = (size_t)b * 10 * WH + (size_t)w * 256 + h;
#pragma unroll
    for (int c = 0; c < 9; ++c) {
        float v = off_buf[obase + (size_t)c * WH];
        int g = c >> 1;
        float s1 = stats1[(b * 5 + g) * 2 + 0];
        float q1 = stats1[(b * 5 + g) * 2 + 1];
        float mean = s1 * INV1;
        float istd = rsqrtf(fmaf(q1, INV1, -(mean * mean)) + 1e-5f);
        v = (v - mean) * istd * go_scale[c] + go_bias[c];
        t9[c] = tanhf(v);
    }
    float ycum[9];
    ycum[3] = t9[3];
    ycum[2] = ycum[3] + t9[2];
    ycum[1] = ycum[2] + t9[1];
    ycum[0] = ycum[1] + t9[0];
    ycum[4] = 0.f;
    ycum[5] = t9[5];
    ycum[6] = ycum[5] + t9[6];
    ycum[7] = ycum[6] + t9[7];
    ycum[8] = ycum[7] + t9[8];

    f32x4 acc[4][2];
#pragma unroll
    for (int i = 0; i < 4; ++i) {
        acc[i][0] = (f32x4){0.f, 0.f, 0.f, 0.f};
        acc[i][1] = (f32x4){0.f, 0.f, 0.f, 0.f};
    }

    const float SC = 255.f / 256.f;

#pragma unroll
    for (int ch = 0; ch < 8; ++ch) {
        asm volatile("s_waitcnt vmcnt(0)" ::: "memory");
        __builtin_amdgcn_sched_barrier(0);
        __syncthreads();
        __builtin_amdgcn_sched_barrier(0);
        if (ch < 7) dma((ch + 1) & 1, ch + 1);   // hidden under gather+MFMA
        const float* tb = tile[ch & 1];

#pragma unroll
        for (int kg = 0; kg < 4; ++kg) {
            bf16x8 pv;
#pragma unroll
            for (int t = 0; t < 2; ++t) {
                int k = kg * 2 + t;
                float py = fminf(fmaxf(((float)w + ycum[k]) * SC, 0.f), 255.f);
                float pxc = fminf(fmaxf((float)(h + k - 4) * SC, 0.f), 255.f);
                float y0f = floorf(py), x0f = floorf(pxc);
                float wy = py - y0f, wx = pxc - x0f;
                int r0 = (int)y0f - row0;
                int r1 = min((int)y0f + 1, 255) - row0;
                int tc = (int)x0f - col0;
                float w00 = (1.f - wy) * (1.f - wx);
                float w01 = (1.f - wy) * wx;
                float w10 = wy * (1.f - wx);
                float w11 = wy * wx;
#pragma unroll
                for (int cl = 0; cl < 4; ++cl) {
                    const float* p0 = tb + (cl * 14 + r0) * 96 + tc;
                    const float* p1 = tb + (cl * 14 + r1) * 96 + tc;
                    float v = fmaf(w00, p0[0],
                              fmaf(w01, p0[1], fmaf(w10, p1[0], w11 * p1[1])));
                    pv[t * 4 + cl] = f2bf(v);
                }
            }
            *(bf16x8*)&Apan[mt * 512 + (kg * 16 + mrow) * 8] = pv;
        }
        {   // tap k=8
            float py = fminf(fmaxf(((float)w + ycum[8]) * SC, 0.f), 255.f);
            float pxc = fminf(fmaxf((float)(h + 4) * SC, 0.f), 255.f);
            float y0f = floorf(py), x0f = floorf(pxc);
            float wy = py - y0f, wx = pxc - x0f;
            int r0 = (int)y0f - row0;
            int r1 = min((int)y0f + 1, 255) - row0;
            int tc = (int)x0f - col0;
            float w00 = (1.f - wy) * (1.f - wx);
            float w01 = (1.f - wy) * wx;
            float w10 = wy * (1.f - wx);
            float w11 = wy * wx;
            bf16x4 pv8;
#pragma unroll
            for (int cl = 0; cl < 4; ++cl) {
                const float* p0 = tb + (cl * 14 + r0) * 96 + tc;
                const float* p1 = tb + (cl * 14 + r1) * 96 + tc;
                float v = fmaf(w00, p0[0],
                          fmaf(w01, p0[1], fmaf(w10, p1[0], w11 * p1[1])));
                pv8[cl] = f2bf(v);
            }
            *(bf16x4*)&A8pan[mt * 512 + ((ch >> 1) * 16 + mrow) * 8 + (ch & 1) * 4] = pv8;
        }
        __syncthreads();   // A-panel ready (gather reads of tb done block-wide)

#pragma unroll
        for (int i = 0; i < 4; ++i) {
            bf16x8 a = *(const bf16x8*)&Apan[((wv * 4 + i) * 64 + lane) * 8];
            acc[i][0] = __builtin_amdgcn_mfma_f32_16x16x32_bf16(a, Bf[ch][0], acc[i][0], 0, 0, 0);
            acc[i][1] = __builtin_amdgcn_mfma_f32_16x16x32_bf16(a, Bf[ch][1], acc[i][1], 0, 0, 0);
        }
    }
#pragma unroll
    for (int i = 0; i < 4; ++i) {          // tap8 K=32 block
        bf16x8 a = *(const bf16x8*)&A8pan[((wv * 4 + i) * 64 + lane) * 8];
        acc[i][0] = __builtin_amdgcn_mfma_f32_16x16x32_bf16(a, B8g[0], acc[i][0], 0, 0, 0);
        acc[i][1] = __builtin_amdgcn_mfma_f32_16x16x32_bf16(a, B8g[1], acc[i][1], 0, 0, 0);
    }

    const int oc0 = lane & 15;
    float bias0 = b_dsc[oc0];
    float bias1 = b_dsc[16 + oc0];
#pragma unroll
    for (int i = 0; i < 4; ++i)
#pragma unroll
        for (int r = 0; r < 4; ++r) { acc[i][0][r] += bias0; acc[i][1][r] += bias1; }

#pragma unroll
    for (int i = 0; i < 4; ++i) {
        int px = (wv * 4 + i) * 16 + (lane >> 4) * 4;
        size_t rowoff = (size_t)(w0 + (px >> 6)) * 256 + h0 + (px & 63);
        *(f32x4*)&pre_out[(size_t)(b * 32 + oc0) * WH + rowoff] = acc[i][0];
        *(f32x4*)&pre_out[(size_t)(b * 32 + 16 + oc0) * WH + rowoff] = acc[i][1];
    }

    // GN2 stats from C-frags: group = oc>>2 (4-col quads)
    float s0 = 0.f, q0 = 0.f, s1 = 0.f, q1 = 0.f;
#pragma unroll
    for (int i = 0; i < 4; ++i)
#pragma unroll
        for (int r = 0; r < 4; ++r) {
            float v0 = acc[i][0][r], v1 = acc[i][1][r];
            s0 += v0; q0 += v0 * v0; s1 += v1; q1 += v1 * v1;
        }
#pragma unroll
    for (int m = 0; m < 4; ++m) {
        int d = (m == 0) ? 1 : (m == 1) ? 2 : (m == 2) ? 16 : 32;
        s0 += __shfl_xor(s0, d, 64); q0 += __shfl_xor(q0, d, 64);
        s1 += __shfl_xor(s1, d, 64); q1 += __shfl_xor(q1, d, 64);
    }
    __syncthreads();
    float* scratch = tile[0];
    if (lane < 16 && !(lane & 3)) {
        int g = lane >> 2;
        scratch[((0 * 4 + g) * 2 + 0) * 4 + wv] = s0;
        scratch[((0 * 4 + g) * 2 + 1) * 4 + wv] = q0;
        scratch[((1 * 4 + g) * 2 + 0) * 4 + wv] = s1;
        scratch[((1 * 4 + g) * 2 + 1) * 4 + wv] = q1;
    }
    __syncthreads();
    if (threadIdx.x < 16) {
        int gg = threadIdx.x >> 1, which = threadIdx.x & 1;
        float sum = scratch[(gg * 2 + which) * 4 + 0] + scratch[(gg * 2 + which) * 4 + 1] +
                    scratch[(gg * 2 + which) * 4 + 2] + scratch[(gg * 2 + which) * 4 + 3];
        atomicAdd(&stats2[(b * 8 + gg) * 2 + which], sum);
    }
}

// ---------------- K5: GN2 finalize (k4 folded in) + apply + ReLU, float4 ----------
__global__ __launch_bounds__(256) void k5_gn(float4* __restrict__ out,
                                             const float* __restrict__ stats2,
                                             const float* __restrict__ gs,
                                             const float* __restrict__ gb) {
    int idx = blockIdx.x * 256 + threadIdx.x;
    int bo = idx >> 14;
    int b = bo >> 5;
    int o = bo & 31;
    int g = o >> 2;
    const float INV2 = 1.f / (4.f * WH);   // 2^-18, exact
    float s = stats2[(b * 8 + g) * 2 + 0];
    float q = stats2[(b * 8 + g) * 2 + 1];
    float mean = s * INV2;
    float istd = rsqrtf(fmaf(q, INV2, -(mean * mean)) + 1e-5f);
    float sc = gs[o] * istd;
    float bi = gb[o] - mean * sc;
    float4 v = out[idx];
    v.x = fmaxf(fmaf(v.x, sc, bi), 0.f);
    v.y = fmaxf(fmaf(v.y, sc, bi), 0.f);
    v.z = fmaxf(fmaf(v.z, sc, bi), 0.f);
    v.w = fmaxf(fmaf(v.w, sc, bi), 0.f);
    out[idx] = v;
}

extern "C" void kernel_launch(void* const* d_in, const int* in_sizes, int n_in,
                              void* d_out, int out_size, void* d_ws, size_t ws_size,
                              hipStream_t stream) {
    const float* x        = (const float*)d_in[0];
    const float* w_off    = (const float*)d_in[1];
    const float* b_off    = (const float*)d_in[2];
    const float* go_scale = (const float*)d_in[3];
    const float* go_bias  = (const float*)d_in[4];
    const float* w_dsc    = (const float*)d_in[5];
    const float* b_dsc    = (const float*)d_in[6];
    const float* gn_scale = (const float*)d_in[7];
    const float* gn_bias  = (const float*)d_in[8];
    float* out = (float*)d_out;

    float* ws = (float*)d_ws;
    float* off_buf = ws;                                    // 2,621,440 f
    unsigned short* B3f  = (unsigned short*)(ws + 2621440); // 8192 us (4096 f)
    unsigned short* B8f  = (unsigned short*)(ws + 2625536); // 1024 us (512 f)
    unsigned short* B1f  = (unsigned short*)(ws + 2626048); // 4096 us (2048 f)
    unsigned short* B18f = (unsigned short*)(ws + 2628096); // 512 us (256 f)
    float* stats1 = ws + 2628352;                           // 40
    float* stats2 = stats1 + 80;                            // 64

    k0_init<<<54, 256, 0, stream>>>(w_dsc, w_off, B3f, B8f, B1f, B18f, stats1, stats2);
    k1_conv<<<dim3(2, 128, BB), 256, 0, stream>>>(x, B1f, B18f, b_off, off_buf, stats1);
    k3_sample<<<dim3(4, 64, BB), 256, 0, stream>>>(x, off_buf, stats1, go_scale, go_bias,
                                                   B3f, B8f, b_dsc, out, stats2);
    k5_gn<<<8192, 256, 0, stream>>>((float4*)out, stats2, gn_scale, gn_bias);
}

// Round 14
// 178.525 us; speedup vs baseline: 1.0162x; 1.0162x over previous
//
#include <hip/hip_runtime.h>
#include <hip/hip_bf16.h>

#define BB 4
#define CC 32
#define WW 256
#define HH 256
#define WH (WW*HH)

typedef __attribute__((ext_vector_type(8))) short bf16x8;
typedef __attribute__((ext_vector_type(4))) short bf16x4;
typedef __attribute__((ext_vector_type(4))) float f32x4;

typedef __attribute__((address_space(1))) const void gvoid;
typedef __attribute__((address_space(3))) void lvoid;

__device__ __forceinline__ short f2bf(float x) {   // RNE fp32->bf16
    union { float f; unsigned u; } a; a.f = x;
    unsigned r = (a.u + 0x7FFF + ((a.u >> 16) & 1)) >> 16;
    return (short)r;
}

// ---------------- K0: build B-fragment tables (bf16, frag-linear) + zero stats ----
__global__ void k0_init(const float* __restrict__ w_dsc, const float* __restrict__ w_off,
                        unsigned short* __restrict__ B3f, unsigned short* __restrict__ B8f,
                        unsigned short* __restrict__ B1f, unsigned short* __restrict__ B18f,
                        float* __restrict__ stats1, float* __restrict__ stats2) {
    int i = blockIdx.x * 256 + threadIdx.x;
    if (i < 8192) {                       // k3 main: [ch][nt][lane][j]
        int j = i & 7, l = (i >> 3) & 63, nt = (i >> 9) & 1, ch = i >> 10;
        int o = nt * 16 + (l & 15);
        int kl = ((l >> 4) << 3) | j;
        int tap = kl >> 2, cl = kl & 3;
        B3f[i] = (unsigned short)f2bf(w_dsc[(o * 32 + ch * 4 + cl) * 9 + tap]);
    } else if (i < 9216) {                // k3 tap8: [nt][lane][j], k8 = channel
        int e = i - 8192;
        int j = e & 7, l = (e >> 3) & 63, nt = e >> 9;
        int o = nt * 16 + (l & 15);
        int k8 = ((l >> 4) << 3) | j;
        B8f[e] = (unsigned short)f2bf(w_dsc[(o * 32 + k8) * 9 + 8]);
    } else if (i < 13312) {               // k1 main: [ch][lane][j], N=16 (10 real)
        int e = i - 9216;
        int j = e & 7, l = (e >> 3) & 63, ch = e >> 9;
        int o = l & 15;
        int kl = ((l >> 4) << 3) | j;
        int tap = kl >> 2, cl = kl & 3;
        B1f[e] = (o < 10) ? (unsigned short)f2bf(w_off[(o * 32 + ch * 4 + cl) * 9 + tap]) : 0;
    } else if (i < 13824) {               // k1 tap8
        int e = i - 13312;
        int j = e & 7, l = (e >> 3) & 63;
        int o = l & 15;
        int k8 = ((l >> 4) << 3) | j;
        B18f[e] = (o < 10) ? (unsigned short)f2bf(w_off[(o * 32 + k8) * 9 + 8]) : 0;
    }
    if (i < 40) stats1[i] = 0.f;
    if (i < 64) stats2[i] = 0.f;
}

// ---------------- K1: 3x3 SAME conv (10 oc) as implicit MFMA GEMM ----------------
// R11 form (passing): full-tile channel-last staging + direct A-fragment reads.
// UNCHANGED.
__global__ __launch_bounds__(256, 4) void k1_conv(
    const float* __restrict__ x, const unsigned short* __restrict__ B1f,
    const unsigned short* __restrict__ B18f, const float* __restrict__ b_off,
    float* __restrict__ off_buf, float* __restrict__ stats1) {
    __shared__ __align__(16) unsigned short tbf[8 * 4 * 136 * 4];  // 34,816 B
    __shared__ float scr[40];

    const int b = blockIdx.z;
    const int w0 = blockIdx.y * 2;
    const int h0 = blockIdx.x * 128;
    const int p = threadIdx.x;
    const int lane = p & 63;
    const int wv = p >> 6;

    const float* xb = x + (size_t)b * CC * WH;

#pragma unroll
    for (int u = 0; u < 5; ++u) {
        if (u < 4 || p < 64) {
            int s = p + u * 256;
            int g = s / 136;
            int rem = s - g * 136;
            int r = rem / 34;
            int k = rem - r * 34;
            int y = w0 - 1 + r;
            int g0 = h0 - 4 + (k << 2);
            f32x4 v0 = {0.f,0.f,0.f,0.f}, v1 = v0, v2 = v0, v3 = v0;
            if (y >= 0 && y < 256 && g0 >= 0 && g0 <= 252) {
                const float* bp2 = xb + y * 256 + g0;
                v0 = *(const f32x4*)(bp2 + (size_t)(g * 4 + 0) * WH);
                v1 = *(const f32x4*)(bp2 + (size_t)(g * 4 + 1) * WH);
                v2 = *(const f32x4*)(bp2 + (size_t)(g * 4 + 2) * WH);
                v3 = *(const f32x4*)(bp2 + (size_t)(g * 4 + 3) * WH);
            }
            int base = ((g * 4 + r) * 136 + (k << 2)) * 4;
#pragma unroll
            for (int i = 0; i < 4; ++i) {
                bf16x4 pv;
                pv[0] = f2bf(v0[i]); pv[1] = f2bf(v1[i]);
                pv[2] = f2bf(v2[i]); pv[3] = f2bf(v3[i]);
                *(bf16x4*)&tbf[base + i * 4] = pv;
            }
        }
    }

    bf16x8 Bf[8], B8g;
    {
        const bf16x8* bp = (const bf16x8*)B1f;
#pragma unroll
        for (int ch = 0; ch < 8; ++ch) Bf[ch] = bp[ch * 64 + lane];
        B8g = ((const bf16x8*)B18f)[lane];
    }

    f32x4 acc[4];
#pragma unroll
    for (int i = 0; i < 4; ++i) acc[i] = (f32x4){0.f, 0.f, 0.f, 0.f};

    const int kg = lane >> 4;
    const int tapL = kg * 2, tapH = tapL + 1;
    const int dyL = tapL / 3, dxL = tapL - dyL * 3;
    const int dyH = tapH / 3, dxH = tapH - dyH * 3;
    int loA[4], hiA[4], t8A[4];
#pragma unroll
    for (int i = 0; i < 4; ++i) {
        int pp = (wv * 4 + i) * 16 + (lane & 15);
        int hlp = pp & 127, wip = pp >> 7;
        loA[i] = ((wip + dyL) * 136 + hlp + dxL + 3) * 4;
        hiA[i] = ((wip + dyH) * 136 + hlp + dxH + 3) * 4;
        t8A[i] = (((kg * 2) * 4 + wip + 2) * 136 + hlp + 5) * 4;
    }

    __syncthreads();   // tile staged; read-only below

#pragma unroll
    for (int ch = 0; ch < 8; ++ch) {
        const int cb = ch * 2176;
#pragma unroll
        for (int i = 0; i < 4; ++i) {
            bf16x4 lo = *(const bf16x4*)&tbf[cb + loA[i]];
            bf16x4 hi = *(const bf16x4*)&tbf[cb + hiA[i]];
            bf16x8 a;
#pragma unroll
            for (int e = 0; e < 4; ++e) { a[e] = lo[e]; a[4 + e] = hi[e]; }
            acc[i] = __builtin_amdgcn_mfma_f32_16x16x32_bf16(a, Bf[ch], acc[i], 0, 0, 0);
        }
    }
#pragma unroll
    for (int i = 0; i < 4; ++i) {          // tap8 K=32 block: k8 = channel
        bf16x4 lo = *(const bf16x4*)&tbf[t8A[i]];
        bf16x4 hi = *(const bf16x4*)&tbf[t8A[i] + 2176];
        bf16x8 a;
#pragma unroll
        for (int e = 0; e < 4; ++e) { a[e] = lo[e]; a[4 + e] = hi[e]; }
        acc[i] = __builtin_amdgcn_mfma_f32_16x16x32_bf16(a, B8g, acc[i], 0, 0, 0);
    }

    const int oc = lane & 15;
    float bias = (oc < 10) ? b_off[oc] : 0.f;
#pragma unroll
    for (int i = 0; i < 4; ++i)
#pragma unroll
        for (int r = 0; r < 4; ++r) acc[i][r] += bias;

    if (oc < 10) {
#pragma unroll
        for (int i = 0; i < 4; ++i) {
            int px = (wv * 4 + i) * 16 + (lane >> 4) * 4;
            size_t addr = (size_t)(b * 10 + oc) * WH +
                          (size_t)(w0 + (px >> 7)) * 256 + h0 + (px & 127);
            *(f32x4*)&off_buf[addr] = acc[i];
        }
    }

    // GN1 stats from C-frags (cols = oc; oc>=10 are exact zeros)
    float s = 0.f, q = 0.f;
#pragma unroll
    for (int i = 0; i < 4; ++i)
#pragma unroll
        for (int r = 0; r < 4; ++r) { float v = acc[i][r]; s += v; q += v * v; }
    s += __shfl_xor(s, 1, 64);  q += __shfl_xor(q, 1, 64);
    s += __shfl_xor(s, 16, 64); q += __shfl_xor(q, 16, 64);
    s += __shfl_xor(s, 32, 64); q += __shfl_xor(q, 32, 64);
    __syncthreads();
    if (lane < 10 && !(lane & 1)) {
        int g = lane >> 1;
        scr[(g * 2 + 0) * 4 + wv] = s;
        scr[(g * 2 + 1) * 4 + wv] = q;
    }
    __syncthreads();
    if (threadIdx.x < 10) {
        int g = threadIdx.x >> 1, which = threadIdx.x & 1;
        float sum = scr[(g * 2 + which) * 4 + 0] + scr[(g * 2 + which) * 4 + 1] +
                    scr[(g * 2 + which) * 4 + 2] + scr[(g * 2 + which) * 4 + 3];
        atomicAdd(&stats1[(b * 5 + g) * 2 + which], sum);
    }
}

// ---------------- K3: bilinear sampling as implicit MFMA GEMM ---------------------
// R10/R11 body UNCHANGED. R14: 1-D launch + bijective XCD-chunk swizzle (T1):
// 1024 blocks, swz=(bid&7)*128+(bid>>3) gives each XCD a contiguous 32-wy x 4-hx
// slab -> staged-row overlap (10/14 rows between w-neighbors) becomes L2-local.
// Pure blockIdx remap: no sync/dataflow change; bijective since 1024 % 8 == 0.
__global__ __launch_bounds__(256, 2) void k3_sample(
    const float* __restrict__ xin, const float* __restrict__ off_buf,
    const float* __restrict__ stats1, const float* __restrict__ go_scale,
    const float* __restrict__ go_bias, const unsigned short* __restrict__ B3f,
    const unsigned short* __restrict__ B8f, const float* __restrict__ b_dsc,
    float* __restrict__ pre_out, float* __restrict__ stats2) {
    __shared__ __align__(16) float tile[2][4 * 14 * 96];  // 2 x 21,504 B
    __shared__ __align__(16) short Apan[16 * 64 * 8];     // 16 KB
    __shared__ __align__(16) short A8pan[16 * 64 * 8];    // 16 KB

    const int bid = blockIdx.x;
    const int swz = (bid & 7) * 128 + (bid >> 3);   // XCD-contiguous chunks
    const int b  = swz >> 8;
    const int rem = swz & 255;
    const int w0 = (rem >> 2) * 4;
    const int h0 = (rem & 3) * 64;
    const int p = threadIdx.x;
    const int lane = p & 63;
    const int wv = p >> 6;
    const int h = h0 + (p & 63);
    const int w = w0 + (p >> 6);
    const int mt = p >> 4;
    const int mrow = p & 15;
    const int row0 = w0 - 5;
    const int col0 = h0 - 8;

    const float* xb = xin + (size_t)b * CC * WH;

    auto dma = [&](int buf, int chn) {
#pragma unroll
        for (int u = 0; u < 6; ++u) {
            if (u < 5 || p < 64) {
                int t = p + u * 256;
                int c = t / 336;
                int rem2 = t - c * 336;
                int r = rem2 / 24;
                int cf4 = rem2 - r * 24;
                int y = min(max(row0 + r, 0), 255);
                int g0 = min(max(col0 + (cf4 << 2), 0), 252);
                const float* gp = xb + (size_t)(chn * 4 + c) * WH + y * 256 + g0;
                __builtin_amdgcn_global_load_lds((gvoid*)gp,
                                                 (lvoid*)&tile[buf][t * 4], 16, 0, 0);
            }
        }
    };

    dma(0, 0);   // in flight under B-frag loads + offsets/tanh phase

    bf16x8 Bf[8][2], B8g[2];
    {
        const bf16x8* bp = (const bf16x8*)B3f;
#pragma unroll
        for (int ch = 0; ch < 8; ++ch) {
            Bf[ch][0] = bp[(ch * 2 + 0) * 64 + lane];
            Bf[ch][1] = bp[(ch * 2 + 1) * 64 + lane];
        }
        B8g[0] = ((const bf16x8*)B8f)[lane];
        B8g[1] = ((const bf16x8*)B8f)[64 + lane];
    }

    // offsets: GN1 (inline finalize from stats1) + tanh + cumsum (per own pixel)
    const float INV1 = 1.f / (2.f * WH);   // 2^-17, exact
    float t9[9];
    size_t obase = (size_t)b * 10 * WH + (size_t)w * 256 + h;
#pragma unroll
    for (int c = 0; c < 9; ++c) {
        float v = off_buf[obase + (size_t)c * WH];
        int g = c >> 1;
        float s1 = stats1[(b * 5 + g) * 2 + 0];
        float q1 = stats1[(b * 5 + g) * 2 + 1];
        float mean = s1 * INV1;
        float istd = rsqrtf(fmaf(q1, INV1, -(mean * mean)) + 1e-5f);
        v = (v - mean) * istd * go_scale[c] + go_bias[c];
        t9[c] = tanhf(v);
    }
    float ycum[9];
    ycum[3] = t9[3];
    ycum[2] = ycum[3] + t9[2];
    ycum[1] = ycum[2] + t9[1];
    ycum[0] = ycum[1] + t9[0];
    ycum[4] = 0.f;
    ycum[5] = t9[5];
    ycum[6] = ycum[5] + t9[6];
    ycum[7] = ycum[6] + t9[7];
    ycum[8] = ycum[7] + t9[8];

    f32x4 acc[4][2];
#pragma unroll
    for (int i = 0; i < 4; ++i) {
        acc[i][0] = (f32x4){0.f, 0.f, 0.f, 0.f};
        acc[i][1] = (f32x4){0.f, 0.f, 0.f, 0.f};
    }

    const float SC = 255.f / 256.f;

#pragma unroll
    for (int ch = 0; ch < 8; ++ch) {
        asm volatile("s_waitcnt vmcnt(0)" ::: "memory");
        __builtin_amdgcn_sched_barrier(0);
        __syncthreads();
        __builtin_amdgcn_sched_barrier(0);
        if (ch < 7) dma((ch + 1) & 1, ch + 1);   // hidden under gather+MFMA
        const float* tb = tile[ch & 1];

#pragma unroll
        for (int kg = 0; kg < 4; ++kg) {
            bf16x8 pv;
#pragma unroll
            for (int t = 0; t < 2; ++t) {
                int k = kg * 2 + t;
                float py = fminf(fmaxf(((float)w + ycum[k]) * SC, 0.f), 255.f);
                float pxc = fminf(fmaxf((float)(h + k - 4) * SC, 0.f), 255.f);
                float y0f = floorf(py), x0f = floorf(pxc);
                float wy = py - y0f, wx = pxc - x0f;
                int r0 = (int)y0f - row0;
                int r1 = min((int)y0f + 1, 255) - row0;
                int tc = (int)x0f - col0;
                float w00 = (1.f - wy) * (1.f - wx);
                float w01 = (1.f - wy) * wx;
                float w10 = wy * (1.f - wx);
                float w11 = wy * wx;
#pragma unroll
                for (int cl = 0; cl < 4; ++cl) {
                    const float* p0 = tb + (cl * 14 + r0) * 96 + tc;
                    const float* p1 = tb + (cl * 14 + r1) * 96 + tc;
                    float v = fmaf(w00, p0[0],
                              fmaf(w01, p0[1], fmaf(w10, p1[0], w11 * p1[1])));
                    pv[t * 4 + cl] = f2bf(v);
                }
            }
            *(bf16x8*)&Apan[mt * 512 + (kg * 16 + mrow) * 8] = pv;
        }
        {   // tap k=8
            float py = fminf(fmaxf(((float)w + ycum[8]) * SC, 0.f), 255.f);
            float pxc = fminf(fmaxf((float)(h + 4) * SC, 0.f), 255.f);
            float y0f = floorf(py), x0f = floorf(pxc);
            float wy = py - y0f, wx = pxc - x0f;
            int r0 = (int)y0f - row0;
            int r1 = min((int)y0f + 1, 255) - row0;
            int tc = (int)x0f - col0;
            float w00 = (1.f - wy) * (1.f - wx);
            float w01 = (1.f - wy) * wx;
            float w10 = wy * (1.f - wx);
            float w11 = wy * wx;
            bf16x4 pv8;
#pragma unroll
            for (int cl = 0; cl < 4; ++cl) {
                const float* p0 = tb + (cl * 14 + r0) * 96 + tc;
                const float* p1 = tb + (cl * 14 + r1) * 96 + tc;
                float v = fmaf(w00, p0[0],
                          fmaf(w01, p0[1], fmaf(w10, p1[0], w11 * p1[1])));
                pv8[cl] = f2bf(v);
            }
            *(bf16x4*)&A8pan[mt * 512 + ((ch >> 1) * 16 + mrow) * 8 + (ch & 1) * 4] = pv8;
        }
        __syncthreads();   // A-panel ready (gather reads of tb done block-wide)

#pragma unroll
        for (int i = 0; i < 4; ++i) {
            bf16x8 a = *(const bf16x8*)&Apan[((wv * 4 + i) * 64 + lane) * 8];
            acc[i][0] = __builtin_amdgcn_mfma_f32_16x16x32_bf16(a, Bf[ch][0], acc[i][0], 0, 0, 0);
            acc[i][1] = __builtin_amdgcn_mfma_f32_16x16x32_bf16(a, Bf[ch][1], acc[i][1], 0, 0, 0);
        }
    }
#pragma unroll
    for (int i = 0; i < 4; ++i) {          // tap8 K=32 block
        bf16x8 a = *(const bf16x8*)&A8pan[((wv * 4 + i) * 64 + lane) * 8];
        acc[i][0] = __builtin_amdgcn_mfma_f32_16x16x32_bf16(a, B8g[0], acc[i][0], 0, 0, 0);
        acc[i][1] = __builtin_amdgcn_mfma_f32_16x16x32_bf16(a, B8g[1], acc[i][1], 0, 0, 0);
    }

    const int oc0 = lane & 15;
    float bias0 = b_dsc[oc0];
    float bias1 = b_dsc[16 + oc0];
#pragma unroll
    for (int i = 0; i < 4; ++i)
#pragma unroll
        for (int r = 0; r < 4; ++r) { acc[i][0][r] += bias0; acc[i][1][r] += bias1; }

#pragma unroll
    for (int i = 0; i < 4; ++i) {
        int px = (wv * 4 + i) * 16 + (lane >> 4) * 4;
        size_t rowoff = (size_t)(w0 + (px >> 6)) * 256 + h0 + (px & 63);
        *(f32x4*)&pre_out[(size_t)(b * 32 + oc0) * WH + rowoff] = acc[i][0];
        *(f32x4*)&pre_out[(size_t)(b * 32 + 16 + oc0) * WH + rowoff] = acc[i][1];
    }

    // GN2 stats from C-frags: group = oc>>2 (4-col quads)
    float s0 = 0.f, q0 = 0.f, s1 = 0.f, q1 = 0.f;
#pragma unroll
    for (int i = 0; i < 4; ++i)
#pragma unroll
        for (int r = 0; r < 4; ++r) {
            float v0 = acc[i][0][r], v1 = acc[i][1][r];
            s0 += v0; q0 += v0 * v0; s1 += v1; q1 += v1 * v1;
        }
#pragma unroll
    for (int m = 0; m < 4; ++m) {
        int d = (m == 0) ? 1 : (m == 1) ? 2 : (m == 2) ? 16 : 32;
        s0 += __shfl_xor(s0, d, 64); q0 += __shfl_xor(q0, d, 64);
        s1 += __shfl_xor(s1, d, 64); q1 += __shfl_xor(q1, d, 64);
    }
    __syncthreads();
    float* scratch = tile[0];
    if (lane < 16 && !(lane & 3)) {
        int g = lane >> 2;
        scratch[((0 * 4 + g) * 2 + 0) * 4 + wv] = s0;
        scratch[((0 * 4 + g) * 2 + 1) * 4 + wv] = q0;
        scratch[((1 * 4 + g) * 2 + 0) * 4 + wv] = s1;
        scratch[((1 * 4 + g) * 2 + 1) * 4 + wv] = q1;
    }
    __syncthreads();
    if (threadIdx.x < 16) {
        int gg = threadIdx.x >> 1, which = threadIdx.x & 1;
        float sum = scratch[(gg * 2 + which) * 4 + 0] + scratch[(gg * 2 + which) * 4 + 1] +
                    scratch[(gg * 2 + which) * 4 + 2] + scratch[(gg * 2 + which) * 4 + 3];
        atomicAdd(&stats2[(b * 8 + gg) * 2 + which], sum);
    }
}

// ---------------- K5: GN2 finalize + apply + ReLU, float4, grid-strided -----------
__global__ __launch_bounds__(256) void k5_gn(float4* __restrict__ out,
                                             const float* __restrict__ stats2,
                                             const float* __restrict__ gs,
                                             const float* __restrict__ gb) {
    const float INV2 = 1.f / (4.f * WH);   // 2^-18, exact
    for (int idx = blockIdx.x * 256 + threadIdx.x; idx < 2097152; idx += 2048 * 256) {
        int bo = idx >> 14;
        int b = bo >> 5;
        int o = bo & 31;
        int g = o >> 2;
        float s = stats2[(b * 8 + g) * 2 + 0];
        float q = stats2[(b * 8 + g) * 2 + 1];
        float mean = s * INV2;
        float istd = rsqrtf(fmaf(q, INV2, -(mean * mean)) + 1e-5f);
        float sc = gs[o] * istd;
        float bi = gb[o] - mean * sc;
        float4 v = out[idx];
        v.x = fmaxf(fmaf(v.x, sc, bi), 0.f);
        v.y = fmaxf(fmaf(v.y, sc, bi), 0.f);
        v.z = fmaxf(fmaf(v.z, sc, bi), 0.f);
        v.w = fmaxf(fmaf(v.w, sc, bi), 0.f);
        out[idx] = v;
    }
}

extern "C" void kernel_launch(void* const* d_in, const int* in_sizes, int n_in,
                              void* d_out, int out_size, void* d_ws, size_t ws_size,
                              hipStream_t stream) {
    const float* x        = (const float*)d_in[0];
    const float* w_off    = (const float*)d_in[1];
    const float* b_off    = (const float*)d_in[2];
    const float* go_scale = (const float*)d_in[3];
    const float* go_bias  = (const float*)d_in[4];
    const float* w_dsc    = (const float*)d_in[5];
    const float* b_dsc    = (const float*)d_in[6];
    const float* gn_scale = (const float*)d_in[7];
    const float* gn_bias  = (const float*)d_in[8];
    float* out = (float*)d_out;

    float* ws = (float*)d_ws;
    float* off_buf = ws;                                    // 2,621,440 f
    unsigned short* B3f  = (unsigned short*)(ws + 2621440); // 8192 us (4096 f)
    unsigned short* B8f  = (unsigned short*)(ws + 2625536); // 1024 us (512 f)
    unsigned short* B1f  = (unsigned short*)(ws + 2626048); // 4096 us (2048 f)
    unsigned short* B18f = (unsigned short*)(ws + 2628096); // 512 us (256 f)
    float* stats1 = ws + 2628352;                           // 40
    float* stats2 = stats1 + 80;                            // 64

    k0_init<<<54, 256, 0, stream>>>(w_dsc, w_off, B3f, B8f, B1f, B18f, stats1, stats2);
    k1_conv<<<dim3(2, 128, BB), 256, 0, stream>>>(x, B1f, B18f, b_off, off_buf, stats1);
    k3_sample<<<1024, 256, 0, stream>>>(x, off_buf, stats1, go_scale, go_bias,
                                        B3f, B8f, b_dsc, out, stats2);
    k5_gn<<<2048, 256, 0, stream>>>((float4*)out, stats2, gn_scale, gn_bias);
}

// Round 15
// 172.831 us; speedup vs baseline: 1.0496x; 1.0329x over previous
//
#include <hip/hip_runtime.h>
#include <hip/hip_bf16.h>

#define BB 4
#define CC 32
#define WW 256
#define HH 256
#define WH (WW*HH)

typedef __attribute__((ext_vector_type(8))) short bf16x8;
typedef __attribute__((ext_vector_type(4))) short bf16x4;
typedef __attribute__((ext_vector_type(4))) float f32x4;

typedef __attribute__((address_space(1))) const void gvoid;
typedef __attribute__((address_space(3))) void lvoid;

__device__ __forceinline__ short f2bf(float x) {   // RNE fp32->bf16
    union { float f; unsigned u; } a; a.f = x;
    unsigned r = (a.u + 0x7FFF + ((a.u >> 16) & 1)) >> 16;
    return (short)r;
}

// ---------------- K0: build B-fragment tables (bf16, frag-linear) + zero stats ----
__global__ void k0_init(const float* __restrict__ w_dsc, const float* __restrict__ w_off,
                        unsigned short* __restrict__ B3f, unsigned short* __restrict__ B8f,
                        unsigned short* __restrict__ B1f, unsigned short* __restrict__ B18f,
                        float* __restrict__ stats1, float* __restrict__ stats2) {
    int i = blockIdx.x * 256 + threadIdx.x;
    if (i < 8192) {                       // k3 main: [ch][nt][lane][j]
        int j = i & 7, l = (i >> 3) & 63, nt = (i >> 9) & 1, ch = i >> 10;
        int o = nt * 16 + (l & 15);
        int kl = ((l >> 4) << 3) | j;
        int tap = kl >> 2, cl = kl & 3;
        B3f[i] = (unsigned short)f2bf(w_dsc[(o * 32 + ch * 4 + cl) * 9 + tap]);
    } else if (i < 9216) {                // k3 tap8: [nt][lane][j], k8 = channel
        int e = i - 8192;
        int j = e & 7, l = (e >> 3) & 63, nt = e >> 9;
        int o = nt * 16 + (l & 15);
        int k8 = ((l >> 4) << 3) | j;
        B8f[e] = (unsigned short)f2bf(w_dsc[(o * 32 + k8) * 9 + 8]);
    } else if (i < 13312) {               // k1 main: [ch][lane][j], N=16 (10 real)
        int e = i - 9216;
        int j = e & 7, l = (e >> 3) & 63, ch = e >> 9;
        int o = l & 15;
        int kl = ((l >> 4) << 3) | j;
        int tap = kl >> 2, cl = kl & 3;
        B1f[e] = (o < 10) ? (unsigned short)f2bf(w_off[(o * 32 + ch * 4 + cl) * 9 + tap]) : 0;
    } else if (i < 13824) {               // k1 tap8
        int e = i - 13312;
        int j = e & 7, l = (e >> 3) & 63;
        int o = l & 15;
        int k8 = ((l >> 4) << 3) | j;
        B18f[e] = (o < 10) ? (unsigned short)f2bf(w_off[(o * 32 + k8) * 9 + 8]) : 0;
    }
    if (i < 40) stats1[i] = 0.f;
    if (i < 64) stats2[i] = 0.f;
}

// ---------------- K1: 3x3 SAME conv (10 oc) as implicit MFMA GEMM ----------------
// R11 body UNCHANGED. R15: 1-D launch + bijective XCD-chunk swizzle (T1, same as
// k3's R14 win): w-pair neighbors share 2/4 staged rows x 136 cols x 32 ch ->
// making them XCD-local turns the overlap into L2 hits. Pure blockIdx remap.
__global__ __launch_bounds__(256, 4) void k1_conv(
    const float* __restrict__ x, const unsigned short* __restrict__ B1f,
    const unsigned short* __restrict__ B18f, const float* __restrict__ b_off,
    float* __restrict__ off_buf, float* __restrict__ stats1) {
    __shared__ __align__(16) unsigned short tbf[8 * 4 * 136 * 4];  // 34,816 B
    __shared__ float scr[40];

    const int bid = blockIdx.x;
    const int swz = (bid & 7) * 128 + (bid >> 3);   // XCD-contiguous chunks (bijective, 1024%8==0)
    const int b  = swz >> 8;
    const int rem = swz & 255;
    const int w0 = (rem >> 1) * 2;
    const int h0 = (rem & 1) * 128;
    const int p = threadIdx.x;
    const int lane = p & 63;
    const int wv = p >> 6;

    const float* xb = x + (size_t)b * CC * WH;

#pragma unroll
    for (int u = 0; u < 5; ++u) {
        if (u < 4 || p < 64) {
            int s = p + u * 256;
            int g = s / 136;
            int rem2 = s - g * 136;
            int r = rem2 / 34;
            int k = rem2 - r * 34;
            int y = w0 - 1 + r;
            int g0 = h0 - 4 + (k << 2);
            f32x4 v0 = {0.f,0.f,0.f,0.f}, v1 = v0, v2 = v0, v3 = v0;
            if (y >= 0 && y < 256 && g0 >= 0 && g0 <= 252) {
                const float* bp2 = xb + y * 256 + g0;
                v0 = *(const f32x4*)(bp2 + (size_t)(g * 4 + 0) * WH);
                v1 = *(const f32x4*)(bp2 + (size_t)(g * 4 + 1) * WH);
                v2 = *(const f32x4*)(bp2 + (size_t)(g * 4 + 2) * WH);
                v3 = *(const f32x4*)(bp2 + (size_t)(g * 4 + 3) * WH);
            }
            int base = ((g * 4 + r) * 136 + (k << 2)) * 4;
#pragma unroll
            for (int i = 0; i < 4; ++i) {
                bf16x4 pv;
                pv[0] = f2bf(v0[i]); pv[1] = f2bf(v1[i]);
                pv[2] = f2bf(v2[i]); pv[3] = f2bf(v3[i]);
                *(bf16x4*)&tbf[base + i * 4] = pv;
            }
        }
    }

    bf16x8 Bf[8], B8g;
    {
        const bf16x8* bp = (const bf16x8*)B1f;
#pragma unroll
        for (int ch = 0; ch < 8; ++ch) Bf[ch] = bp[ch * 64 + lane];
        B8g = ((const bf16x8*)B18f)[lane];
    }

    f32x4 acc[4];
#pragma unroll
    for (int i = 0; i < 4; ++i) acc[i] = (f32x4){0.f, 0.f, 0.f, 0.f};

    const int kg = lane >> 4;
    const int tapL = kg * 2, tapH = tapL + 1;
    const int dyL = tapL / 3, dxL = tapL - dyL * 3;
    const int dyH = tapH / 3, dxH = tapH - dyH * 3;
    int loA[4], hiA[4], t8A[4];
#pragma unroll
    for (int i = 0; i < 4; ++i) {
        int pp = (wv * 4 + i) * 16 + (lane & 15);
        int hlp = pp & 127, wip = pp >> 7;
        loA[i] = ((wip + dyL) * 136 + hlp + dxL + 3) * 4;
        hiA[i] = ((wip + dyH) * 136 + hlp + dxH + 3) * 4;
        t8A[i] = (((kg * 2) * 4 + wip + 2) * 136 + hlp + 5) * 4;
    }

    __syncthreads();   // tile staged; read-only below

#pragma unroll
    for (int ch = 0; ch < 8; ++ch) {
        const int cb = ch * 2176;
#pragma unroll
        for (int i = 0; i < 4; ++i) {
            bf16x4 lo = *(const bf16x4*)&tbf[cb + loA[i]];
            bf16x4 hi = *(const bf16x4*)&tbf[cb + hiA[i]];
            bf16x8 a;
#pragma unroll
            for (int e = 0; e < 4; ++e) { a[e] = lo[e]; a[4 + e] = hi[e]; }
            acc[i] = __builtin_amdgcn_mfma_f32_16x16x32_bf16(a, Bf[ch], acc[i], 0, 0, 0);
        }
    }
#pragma unroll
    for (int i = 0; i < 4; ++i) {          // tap8 K=32 block: k8 = channel
        bf16x4 lo = *(const bf16x4*)&tbf[t8A[i]];
        bf16x4 hi = *(const bf16x4*)&tbf[t8A[i] + 2176];
        bf16x8 a;
#pragma unroll
        for (int e = 0; e < 4; ++e) { a[e] = lo[e]; a[4 + e] = hi[e]; }
        acc[i] = __builtin_amdgcn_mfma_f32_16x16x32_bf16(a, B8g, acc[i], 0, 0, 0);
    }

    const int oc = lane & 15;
    float bias = (oc < 10) ? b_off[oc] : 0.f;
#pragma unroll
    for (int i = 0; i < 4; ++i)
#pragma unroll
        for (int r = 0; r < 4; ++r) acc[i][r] += bias;

    if (oc < 10) {
#pragma unroll
        for (int i = 0; i < 4; ++i) {
            int px = (wv * 4 + i) * 16 + (lane >> 4) * 4;
            size_t addr = (size_t)(b * 10 + oc) * WH +
                          (size_t)(w0 + (px >> 7)) * 256 + h0 + (px & 127);
            *(f32x4*)&off_buf[addr] = acc[i];
        }
    }

    // GN1 stats from C-frags (cols = oc; oc>=10 are exact zeros)
    float s = 0.f, q = 0.f;
#pragma unroll
    for (int i = 0; i < 4; ++i)
#pragma unroll
        for (int r = 0; r < 4; ++r) { float v = acc[i][r]; s += v; q += v * v; }
    s += __shfl_xor(s, 1, 64);  q += __shfl_xor(q, 1, 64);
    s += __shfl_xor(s, 16, 64); q += __shfl_xor(q, 16, 64);
    s += __shfl_xor(s, 32, 64); q += __shfl_xor(q, 32, 64);
    __syncthreads();
    if (lane < 10 && !(lane & 1)) {
        int g = lane >> 1;
        scr[(g * 2 + 0) * 4 + wv] = s;
        scr[(g * 2 + 1) * 4 + wv] = q;
    }
    __syncthreads();
    if (threadIdx.x < 10) {
        int g = threadIdx.x >> 1, which = threadIdx.x & 1;
        float sum = scr[(g * 2 + which) * 4 + 0] + scr[(g * 2 + which) * 4 + 1] +
                    scr[(g * 2 + which) * 4 + 2] + scr[(g * 2 + which) * 4 + 3];
        atomicAdd(&stats1[(b * 5 + g) * 2 + which], sum);
    }
}

// ---------------- K3: bilinear sampling as implicit MFMA GEMM ---------------------
// R14 form (passing, ~61 us): DMA dbuf + vmcnt drains + XCD swizzle. UNCHANGED.
__global__ __launch_bounds__(256, 2) void k3_sample(
    const float* __restrict__ xin, const float* __restrict__ off_buf,
    const float* __restrict__ stats1, const float* __restrict__ go_scale,
    const float* __restrict__ go_bias, const unsigned short* __restrict__ B3f,
    const unsigned short* __restrict__ B8f, const float* __restrict__ b_dsc,
    float* __restrict__ pre_out, float* __restrict__ stats2) {
    __shared__ __align__(16) float tile[2][4 * 14 * 96];  // 2 x 21,504 B
    __shared__ __align__(16) short Apan[16 * 64 * 8];     // 16 KB
    __shared__ __align__(16) short A8pan[16 * 64 * 8];    // 16 KB

    const int bid = blockIdx.x;
    const int swz = (bid & 7) * 128 + (bid >> 3);   // XCD-contiguous chunks
    const int b  = swz >> 8;
    const int rem = swz & 255;
    const int w0 = (rem >> 2) * 4;
    const int h0 = (rem & 3) * 64;
    const int p = threadIdx.x;
    const int lane = p & 63;
    const int wv = p >> 6;
    const int h = h0 + (p & 63);
    const int w = w0 + (p >> 6);
    const int mt = p >> 4;
    const int mrow = p & 15;
    const int row0 = w0 - 5;
    const int col0 = h0 - 8;

    const float* xb = xin + (size_t)b * CC * WH;

    auto dma = [&](int buf, int chn) {
#pragma unroll
        for (int u = 0; u < 6; ++u) {
            if (u < 5 || p < 64) {
                int t = p + u * 256;
                int c = t / 336;
                int rem2 = t - c * 336;
                int r = rem2 / 24;
                int cf4 = rem2 - r * 24;
                int y = min(max(row0 + r, 0), 255);
                int g0 = min(max(col0 + (cf4 << 2), 0), 252);
                const float* gp = xb + (size_t)(chn * 4 + c) * WH + y * 256 + g0;
                __builtin_amdgcn_global_load_lds((gvoid*)gp,
                                                 (lvoid*)&tile[buf][t * 4], 16, 0, 0);
            }
        }
    };

    dma(0, 0);   // in flight under B-frag loads + offsets/tanh phase

    bf16x8 Bf[8][2], B8g[2];
    {
        const bf16x8* bp = (const bf16x8*)B3f;
#pragma unroll
        for (int ch = 0; ch < 8; ++ch) {
            Bf[ch][0] = bp[(ch * 2 + 0) * 64 + lane];
            Bf[ch][1] = bp[(ch * 2 + 1) * 64 + lane];
        }
        B8g[0] = ((const bf16x8*)B8f)[lane];
        B8g[1] = ((const bf16x8*)B8f)[64 + lane];
    }

    // offsets: GN1 (inline finalize from stats1) + tanh + cumsum (per own pixel)
    const float INV1 = 1.f / (2.f * WH);   // 2^-17, exact
    float t9[9];
    size_t obase = (size_t)b * 10 * WH + (size_t)w * 256 + h;
#pragma unroll
    for (int c = 0; c < 9; ++c) {
        float v = off_buf[obase + (size_t)c * WH];
        int g = c >> 1;
        float s1 = stats1[(b * 5 + g) * 2 + 0];
        float q1 = stats1[(b * 5 + g) * 2 + 1];
        float mean = s1 * INV1;
        float istd = rsqrtf(fmaf(q1, INV1, -(mean * mean)) + 1e-5f);
        v = (v - mean) * istd * go_scale[c] + go_bias[c];
        t9[c] = tanhf(v);
    }
    float ycum[9];
    ycum[3] = t9[3];
    ycum[2] = ycum[3] + t9[2];
    ycum[1] = ycum[2] + t9[1];
    ycum[0] = ycum[1] + t9[0];
    ycum[4] = 0.f;
    ycum[5] = t9[5];
    ycum[6] = ycum[5] + t9[6];
    ycum[7] = ycum[6] + t9[7];
    ycum[8] = ycum[7] + t9[8];

    f32x4 acc[4][2];
#pragma unroll
    for (int i = 0; i < 4; ++i) {
        acc[i][0] = (f32x4){0.f, 0.f, 0.f, 0.f};
        acc[i][1] = (f32x4){0.f, 0.f, 0.f, 0.f};
    }

    const float SC = 255.f / 256.f;

#pragma unroll
    for (int ch = 0; ch < 8; ++ch) {
        asm volatile("s_waitcnt vmcnt(0)" ::: "memory");
        __builtin_amdgcn_sched_barrier(0);
        __syncthreads();
        __builtin_amdgcn_sched_barrier(0);
        if (ch < 7) dma((ch + 1) & 1, ch + 1);   // hidden under gather+MFMA
        const float* tb = tile[ch & 1];

#pragma unroll
        for (int kg = 0; kg < 4; ++kg) {
            bf16x8 pv;
#pragma unroll
            for (int t = 0; t < 2; ++t) {
                int k = kg * 2 + t;
                float py = fminf(fmaxf(((float)w + ycum[k]) * SC, 0.f), 255.f);
                float pxc = fminf(fmaxf((float)(h + k - 4) * SC, 0.f), 255.f);
                float y0f = floorf(py), x0f = floorf(pxc);
                float wy = py - y0f, wx = pxc - x0f;
                int r0 = (int)y0f - row0;
                int r1 = min((int)y0f + 1, 255) - row0;
                int tc = (int)x0f - col0;
                float w00 = (1.f - wy) * (1.f - wx);
                float w01 = (1.f - wy) * wx;
                float w10 = wy * (1.f - wx);
                float w11 = wy * wx;
#pragma unroll
                for (int cl = 0; cl < 4; ++cl) {
                    const float* p0 = tb + (cl * 14 + r0) * 96 + tc;
                    const float* p1 = tb + (cl * 14 + r1) * 96 + tc;
                    float v = fmaf(w00, p0[0],
                              fmaf(w01, p0[1], fmaf(w10, p1[0], w11 * p1[1])));
                    pv[t * 4 + cl] = f2bf(v);
                }
            }
            *(bf16x8*)&Apan[mt * 512 + (kg * 16 + mrow) * 8] = pv;
        }
        {   // tap k=8
            float py = fminf(fmaxf(((float)w + ycum[8]) * SC, 0.f), 255.f);
            float pxc = fminf(fmaxf((float)(h + 4) * SC, 0.f), 255.f);
            float y0f = floorf(py), x0f = floorf(pxc);
            float wy = py - y0f, wx = pxc - x0f;
            int r0 = (int)y0f - row0;
            int r1 = min((int)y0f + 1, 255) - row0;
            int tc = (int)x0f - col0;
            float w00 = (1.f - wy) * (1.f - wx);
            float w01 = (1.f - wy) * wx;
            float w10 = wy * (1.f - wx);
            float w11 = wy * wx;
            bf16x4 pv8;
#pragma unroll
            for (int cl = 0; cl < 4; ++cl) {
                const float* p0 = tb + (cl * 14 + r0) * 96 + tc;
                const float* p1 = tb + (cl * 14 + r1) * 96 + tc;
                float v = fmaf(w00, p0[0],
                          fmaf(w01, p0[1], fmaf(w10, p1[0], w11 * p1[1])));
                pv8[cl] = f2bf(v);
            }
            *(bf16x4*)&A8pan[mt * 512 + ((ch >> 1) * 16 + mrow) * 8 + (ch & 1) * 4] = pv8;
        }
        __syncthreads();   // A-panel ready (gather reads of tb done block-wide)

#pragma unroll
        for (int i = 0; i < 4; ++i) {
            bf16x8 a = *(const bf16x8*)&Apan[((wv * 4 + i) * 64 + lane) * 8];
            acc[i][0] = __builtin_amdgcn_mfma_f32_16x16x32_bf16(a, Bf[ch][0], acc[i][0], 0, 0, 0);
            acc[i][1] = __builtin_amdgcn_mfma_f32_16x16x32_bf16(a, Bf[ch][1], acc[i][1], 0, 0, 0);
        }
    }
#pragma unroll
    for (int i = 0; i < 4; ++i) {          // tap8 K=32 block
        bf16x8 a = *(const bf16x8*)&A8pan[((wv * 4 + i) * 64 + lane) * 8];
        acc[i][0] = __builtin_amdgcn_mfma_f32_16x16x32_bf16(a, B8g[0], acc[i][0], 0, 0, 0);
        acc[i][1] = __builtin_amdgcn_mfma_f32_16x16x32_bf16(a, B8g[1], acc[i][1], 0, 0, 0);
    }

    const int oc0 = lane & 15;
    float bias0 = b_dsc[oc0];
    float bias1 = b_dsc[16 + oc0];
#pragma unroll
    for (int i = 0; i < 4; ++i)
#pragma unroll
        for (int r = 0; r < 4; ++r) { acc[i][0][r] += bias0; acc[i][1][r] += bias1; }

#pragma unroll
    for (int i = 0; i < 4; ++i) {
        int px = (wv * 4 + i) * 16 + (lane >> 4) * 4;
        size_t rowoff = (size_t)(w0 + (px >> 6)) * 256 + h0 + (px & 63);
        *(f32x4*)&pre_out[(size_t)(b * 32 + oc0) * WH + rowoff] = acc[i][0];
        *(f32x4*)&pre_out[(size_t)(b * 32 + 16 + oc0) * WH + rowoff] = acc[i][1];
    }

    // GN2 stats from C-frags: group = oc>>2 (4-col quads)
    float s0 = 0.f, q0 = 0.f, s1 = 0.f, q1 = 0.f;
#pragma unroll
    for (int i = 0; i < 4; ++i)
#pragma unroll
        for (int r = 0; r < 4; ++r) {
            float v0 = acc[i][0][r], v1 = acc[i][1][r];
            s0 += v0; q0 += v0 * v0; s1 += v1; q1 += v1 * v1;
        }
#pragma unroll
    for (int m = 0; m < 4; ++m) {
        int d = (m == 0) ? 1 : (m == 1) ? 2 : (m == 2) ? 16 : 32;
        s0 += __shfl_xor(s0, d, 64); q0 += __shfl_xor(q0, d, 64);
        s1 += __shfl_xor(s1, d, 64); q1 += __shfl_xor(q1, d, 64);
    }
    __syncthreads();
    float* scratch = tile[0];
    if (lane < 16 && !(lane & 3)) {
        int g = lane >> 2;
        scratch[((0 * 4 + g) * 2 + 0) * 4 + wv] = s0;
        scratch[((0 * 4 + g) * 2 + 1) * 4 + wv] = q0;
        scratch[((1 * 4 + g) * 2 + 0) * 4 + wv] = s1;
        scratch[((1 * 4 + g) * 2 + 1) * 4 + wv] = q1;
    }
    __syncthreads();
    if (threadIdx.x < 16) {
        int gg = threadIdx.x >> 1, which = threadIdx.x & 1;
        float sum = scratch[(gg * 2 + which) * 4 + 0] + scratch[(gg * 2 + which) * 4 + 1] +
                    scratch[(gg * 2 + which) * 4 + 2] + scratch[(gg * 2 + which) * 4 + 3];
        atomicAdd(&stats2[(b * 8 + gg) * 2 + which], sum);
    }
}

// ---------------- K5: GN2 finalize + apply + ReLU, float4, grid-strided -----------
__global__ __launch_bounds__(256) void k5_gn(float4* __restrict__ out,
                                             const float* __restrict__ stats2,
                                             const float* __restrict__ gs,
                                             const float* __restrict__ gb) {
    const float INV2 = 1.f / (4.f * WH);   // 2^-18, exact
    for (int idx = blockIdx.x * 256 + threadIdx.x; idx < 2097152; idx += 2048 * 256) {
        int bo = idx >> 14;
        int b = bo >> 5;
        int o = bo & 31;
        int g = o >> 2;
        float s = stats2[(b * 8 + g) * 2 + 0];
        float q = stats2[(b * 8 + g) * 2 + 1];
        float mean = s * INV2;
        float istd = rsqrtf(fmaf(q, INV2, -(mean * mean)) + 1e-5f);
        float sc = gs[o] * istd;
        float bi = gb[o] - mean * sc;
        float4 v = out[idx];
        v.x = fmaxf(fmaf(v.x, sc, bi), 0.f);
        v.y = fmaxf(fmaf(v.y, sc, bi), 0.f);
        v.z = fmaxf(fmaf(v.z, sc, bi), 0.f);
        v.w = fmaxf(fmaf(v.w, sc, bi), 0.f);
        out[idx] = v;
    }
}

extern "C" void kernel_launch(void* const* d_in, const int* in_sizes, int n_in,
                              void* d_out, int out_size, void* d_ws, size_t ws_size,
                              hipStream_t stream) {
    const float* x        = (const float*)d_in[0];
    const float* w_off    = (const float*)d_in[1];
    const float* b_off    = (const float*)d_in[2];
    const float* go_scale = (const float*)d_in[3];
    const float* go_bias  = (const float*)d_in[4];
    const float* w_dsc    = (const float*)d_in[5];
    const float* b_dsc    = (const float*)d_in[6];
    const float* gn_scale = (const float*)d_in[7];
    const float* gn_bias  = (const float*)d_in[8];
    float* out = (float*)d_out;

    float* ws = (float*)d_ws;
    float* off_buf = ws;                                    // 2,621,440 f
    unsigned short* B3f  = (unsigned short*)(ws + 2621440); // 8192 us (4096 f)
    unsigned short* B8f  = (unsigned short*)(ws + 2625536); // 1024 us (512 f)
    unsigned short* B1f  = (unsigned short*)(ws + 2626048); // 4096 us (2048 f)
    unsigned short* B18f = (unsigned short*)(ws + 2628096); // 512 us (256 f)
    float* stats1 = ws + 2628352;                           // 40
    float* stats2 = stats1 + 80;                            // 64

    k0_init<<<54, 256, 0, stream>>>(w_dsc, w_off, B3f, B8f, B1f, B18f, stats1, stats2);
    k1_conv<<<1024, 256, 0, stream>>>(x, B1f, B18f, b_off, off_buf, stats1);
    k3_sample<<<1024, 256, 0, stream>>>(x, off_buf, stats1, go_scale, go_bias,
                                        B3f, B8f, b_dsc, out, stats2);
    k5_gn<<<2048, 256, 0, stream>>>((float4*)out, stats2, gn_scale, gn_bias);
}